// Round 2
// baseline (6040.069 us; speedup 1.0000x reference)
//
#include <hip/hip_runtime.h>
#include <math.h>

// Problem constants
#define V_  1024
#define C_  768
#define H_  12
#define L_  8
#define B_  8
#define T_  1024
#define M_  (B_ * T_)      // 8192
#define C3_ (3 * C_)       // 2304
#define C4_ (4 * C_)       // 3072

typedef __bf16 bf16;
typedef __bf16 bf16x8 __attribute__((ext_vector_type(8)));
typedef float  f32x4  __attribute__((ext_vector_type(4)));

// async global->LDS, 16B per lane; LDS dest must be wave-uniform base + lane*16
#define GLDS16(g, l) __builtin_amdgcn_global_load_lds(                       \
    (const __attribute__((address_space(1))) void*)(g),                      \
    (__attribute__((address_space(3))) void*)(l), 16, 0, 0)

// ---------------------------------------------------------------------------
// Embedding: x[b,t,:] = tok[idx] + pos[t] + cls[y[b]]   (f32)
// ---------------------------------------------------------------------------
__global__ __launch_bounds__(256) void embed_kernel(
    const int* __restrict__ idx, const int* __restrict__ y,
    const float* __restrict__ tok, const float* __restrict__ pos,
    const float* __restrict__ cls, float* __restrict__ x) {
    int row = blockIdx.x;
    int b = row >> 10, t = row & (T_ - 1);
    int tid = threadIdx.x;
    const float* tr = tok + (size_t)idx[row] * C_;
    const float* pr = pos + (size_t)t * C_;
    const float* cr = cls + (size_t)y[b] * C_;
    float* xr = x + (size_t)row * C_;
    for (int c = tid; c < C_; c += 256)
        xr[c] = tr[c] + pr[c] + cr[c];
}

// ---------------------------------------------------------------------------
// Block reduce (256 threads)
// ---------------------------------------------------------------------------
__device__ __forceinline__ float block_sum256(float v, float* red) {
#pragma unroll
    for (int off = 32; off > 0; off >>= 1) v += __shfl_down(v, off);
    __syncthreads();
    if ((threadIdx.x & 63) == 0) red[threadIdx.x >> 6] = v;
    __syncthreads();
    return red[0] + red[1] + red[2] + red[3];
}

// ---------------------------------------------------------------------------
// LayerNorm: f32 in -> bf16 out. One block per row, C=768.
// ---------------------------------------------------------------------------
__global__ __launch_bounds__(256) void ln_kernel(
    const float* __restrict__ in, const float* __restrict__ w,
    const float* __restrict__ b, bf16* __restrict__ out) {
    __shared__ float red[4];
    int row = blockIdx.x, tid = threadIdx.x;
    const float* xr = in + (size_t)row * C_;
    float v0 = xr[tid], v1 = xr[tid + 256], v2 = xr[tid + 512];
    float s = block_sum256(v0 + v1 + v2, red);
    float m = s * (1.0f / C_);
    float d0 = v0 - m, d1 = v1 - m, d2 = v2 - m;
    float s2 = block_sum256(d0 * d0 + d1 * d1 + d2 * d2, red);
    float rs = rsqrtf(s2 * (1.0f / C_) + 1e-5f);
    bf16* orow = out + (size_t)row * C_;
    orow[tid]       = (bf16)(d0 * rs * w[tid]       + b[tid]);
    orow[tid + 256] = (bf16)(d1 * rs * w[tid + 256] + b[tid + 256]);
    orow[tid + 512] = (bf16)(d2 * rs * w[tid + 512] + b[tid + 512]);
}

// ---------------------------------------------------------------------------
// Weight transpose + cast: W[K,N] f32 (layer blockIdx.z) -> Wt[N,K] bf16
// ---------------------------------------------------------------------------
__global__ __launch_bounds__(256) void wt_kernel(
    const float* __restrict__ W, bf16* __restrict__ Wt, int K, int N) {
    __shared__ float ts[32][33];
    const size_t sz = (size_t)K * N;
    const float* Ws = W + blockIdx.z * sz;
    bf16* Wts = Wt + blockIdx.z * sz;
    int n0 = blockIdx.x * 32, k0 = blockIdx.y * 32;
    int tx = threadIdx.x & 31, ty = threadIdx.x >> 5;
#pragma unroll
    for (int i = 0; i < 4; ++i)
        ts[ty + i * 8][tx] = Ws[(size_t)(k0 + ty + i * 8) * N + n0 + tx];
    __syncthreads();
#pragma unroll
    for (int i = 0; i < 4; ++i)
        Wts[(size_t)(n0 + ty + i * 8) * K + k0 + tx] = (bf16)ts[tx][ty + i * 8];
}

// ---------------------------------------------------------------------------
// MFMA GEMM: out[M,N] = epilogue(A[M,K]bf16 @ Bt[N,K]bf16^T + bias) (+res f32)
// 128x128 tile, BK=64, 4 waves (2x2), 16x16x32 bf16 MFMA. m97 structure.
// ACT: 0=none 1=exact GELU.  OBF: write bf16 else f32.
// ---------------------------------------------------------------------------
template <int ACT, int BIASF, int RESF, int OBF>
__global__ __launch_bounds__(256) void mfma_gemm(
    const bf16* __restrict__ A, const bf16* __restrict__ Bt,
    const float* __restrict__ bias, const float* __restrict__ res,
    void* __restrict__ outp, int K, int N) {
    __shared__ bf16 As[128 * 64];
    __shared__ bf16 Bs[128 * 64];
    const int tid = threadIdx.x;
    const int lane = tid & 63, wave = tid >> 6;
    const int wr = (wave >> 1) * 64, wc = (wave & 1) * 64;
    const int brow = blockIdx.y * 128, bcol = blockIdx.x * 128;
    const int l15 = lane & 15, l4 = lane >> 4;

    const bf16* Ab = A + (size_t)brow * K;
    const bf16* Bb = Bt + (size_t)bcol * K;

    f32x4 acc[4][4];
#pragma unroll
    for (int m = 0; m < 4; ++m)
#pragma unroll
        for (int n = 0; n < 4; ++n)
            acc[m][n] = (f32x4){0.f, 0.f, 0.f, 0.f};

    for (int kt = 0; kt < K; kt += 64) {
        __syncthreads();   // all waves done reading LDS from previous iter
#pragma unroll
        for (int i = 0; i < 4; ++i) {
            int j = i * 256 + tid;   // 1024 chunks of 16B = 128x64 bf16
            GLDS16(Ab + (size_t)(j >> 3) * K + kt + (j & 7) * 8, As + j * 8);
        }
#pragma unroll
        for (int i = 0; i < 4; ++i) {
            int j = i * 256 + tid;
            GLDS16(Bb + (size_t)(j >> 3) * K + kt + (j & 7) * 8, Bs + j * 8);
        }
        __syncthreads();   // compiler drains vmcnt before barrier
#pragma unroll
        for (int kk = 0; kk < 2; ++kk) {
            bf16x8 af[4], bfr[4];
#pragma unroll
            for (int m = 0; m < 4; ++m)
                af[m] = *(const bf16x8*)(As + (wr + m * 16 + l15) * 64 + kk * 32 + l4 * 8);
#pragma unroll
            for (int n = 0; n < 4; ++n)
                bfr[n] = *(const bf16x8*)(Bs + (wc + n * 16 + l15) * 64 + kk * 32 + l4 * 8);
#pragma unroll
            for (int m = 0; m < 4; ++m)
#pragma unroll
                for (int n = 0; n < 4; ++n)
                    acc[m][n] = __builtin_amdgcn_mfma_f32_16x16x32_bf16(
                        af[m], bfr[n], acc[m][n], 0, 0, 0);
        }
    }

    // epilogue: C/D layout col = lane&15, row = (lane>>4)*4 + reg  [m89/m91]
#pragma unroll
    for (int n = 0; n < 4; ++n) {
        const int col = bcol + wc + n * 16 + l15;
        const float bv = BIASF ? bias[col] : 0.f;
#pragma unroll
        for (int m = 0; m < 4; ++m) {
#pragma unroll
            for (int j = 0; j < 4; ++j) {
                const int row = brow + wr + m * 16 + l4 * 4 + j;
                float v = acc[m][n][j] + bv;
                if (ACT == 1) v = 0.5f * v * (1.f + erff(v * 0.70710678118654752440f));
                if (RESF) v += res[(size_t)row * N + col];
                if (OBF)  ((bf16*)outp)[(size_t)row * N + col] = (bf16)v;
                else      ((float*)outp)[(size_t)row * N + col] = v;
            }
        }
    }
}

// ---------------------------------------------------------------------------
// Tiled causal attention, online softmax. One block per (b, h, 64 q-rows).
// 4 waves: wave w owns q-rows w*16..w*16+15. Lane: ql = lane&15 (q-row),
// kb = (lane>>4)*16 (k-slice for scores / d-slice for output acc).
// qkv f32 [M,3C]; o bf16 [M,C].
// ---------------------------------------------------------------------------
__global__ __launch_bounds__(256) void attn_kernel(
    const float* __restrict__ qkv, bf16* __restrict__ o) {
    __shared__ float Qs[64][68];   // [q][d], pre-scaled
    __shared__ float Ks[64][68];   // transposed: [d][k]
    __shared__ float Vs[64][64];   // [k][d]
    __shared__ float Ps[64][68];   // [q][k], per-wave-exclusive rows

    const int qt = gridDim.x - 1 - blockIdx.x;   // heavy tiles first
    const int bh = blockIdx.y;
    const int b = bh / H_, h = bh % H_;
    const int tid = threadIdx.x;
    const int w = tid >> 6, lane = tid & 63;
    const int ql = lane & 15, kb = (lane >> 4) * 16;
    const int qlocal = w * 16 + ql;

    const float* Qg = qkv + ((size_t)(b * T_) + qt * 64) * C3_ + h * 64;
    const float* Kg = qkv + (size_t)(b * T_) * C3_ + C_ + h * 64;
    const float* Vg = Kg + C_;

#pragma unroll
    for (int i = 0; i < 4; ++i) {
        int e4 = i * 256 + tid;
        int r = e4 >> 4, d = (e4 & 15) * 4;
        float4 qv = *(const float4*)(Qg + (size_t)r * C3_ + d);
        qv.x *= 0.125f; qv.y *= 0.125f; qv.z *= 0.125f; qv.w *= 0.125f;
        *(float4*)&Qs[r][d] = qv;
    }

    float mrun = -1e30f, lsum = 0.f;
    float accv[16];
#pragma unroll
    for (int jd = 0; jd < 16; ++jd) accv[jd] = 0.f;

    for (int ktile = 0; ktile <= qt; ++ktile) {
        __syncthreads();   // prev PV reads done (also covers Qs on iter 0)
#pragma unroll
        for (int i = 0; i < 4; ++i) {
            int e4 = i * 256 + tid;
            int r = e4 >> 4, d = (e4 & 15) * 4;
            *(float4*)&Vs[r][d] =
                *(const float4*)(Vg + (size_t)(ktile * 64 + r) * C3_ + d);
        }
#pragma unroll
        for (int i = 0; i < 16; ++i) {
            int e = i * 256 + tid;
            int r = e >> 6, d = e & 63;
            Ks[d][r] = Kg[(size_t)(ktile * 64 + r) * C3_ + d];
        }
        __syncthreads();

        // scores s[jk] for k = ktile*64 + kb + jk
        float s[16];
#pragma unroll
        for (int jk = 0; jk < 16; ++jk) s[jk] = 0.f;
        for (int d = 0; d < 64; ++d) {
            float qv = Qs[qlocal][d];
#pragma unroll
            for (int j4 = 0; j4 < 4; ++j4) {
                float4 kv = *(const float4*)&Ks[d][kb + j4 * 4];
                s[j4 * 4 + 0] = fmaf(qv, kv.x, s[j4 * 4 + 0]);
                s[j4 * 4 + 1] = fmaf(qv, kv.y, s[j4 * 4 + 1]);
                s[j4 * 4 + 2] = fmaf(qv, kv.z, s[j4 * 4 + 2]);
                s[j4 * 4 + 3] = fmaf(qv, kv.w, s[j4 * 4 + 3]);
            }
        }
        if (ktile == qt) {   // diagonal tile: causal mask
#pragma unroll
            for (int jk = 0; jk < 16; ++jk)
                if (kb + jk > qlocal) s[jk] = -1e30f;
        }
        // row reduce across the 4 lanes sharing this q-row (xor 16, 32)
        float tmax = s[0];
#pragma unroll
        for (int jk = 1; jk < 16; ++jk) tmax = fmaxf(tmax, s[jk]);
        tmax = fmaxf(tmax, __shfl_xor(tmax, 16));
        tmax = fmaxf(tmax, __shfl_xor(tmax, 32));
        float mnew = fmaxf(mrun, tmax);
        float fscale = __expf(mrun - mnew);   // 0 on first tile
        float psum = 0.f;
#pragma unroll
        for (int jk = 0; jk < 16; ++jk) {
            s[jk] = __expf(s[jk] - mnew);
            psum += s[jk];
        }
        psum += __shfl_xor(psum, 16);
        psum += __shfl_xor(psum, 32);
        lsum = lsum * fscale + psum;
        mrun = mnew;
#pragma unroll
        for (int jd = 0; jd < 16; ++jd) accv[jd] *= fscale;
        // P to LDS (wave-private rows; no barrier needed)
#pragma unroll
        for (int jk = 0; jk < 16; ++jk) Ps[qlocal][kb + jk] = s[jk];
        // PV: acc[d] += sum_k P[q][k] * V[k][d], lane's d-slice = kb..kb+15
        for (int k = 0; k < 64; ++k) {
            float p = Ps[qlocal][k];
#pragma unroll
            for (int j4 = 0; j4 < 4; ++j4) {
                float4 vv = *(const float4*)&Vs[k][kb + j4 * 4];
                accv[j4 * 4 + 0] = fmaf(p, vv.x, accv[j4 * 4 + 0]);
                accv[j4 * 4 + 1] = fmaf(p, vv.y, accv[j4 * 4 + 1]);
                accv[j4 * 4 + 2] = fmaf(p, vv.z, accv[j4 * 4 + 2]);
                accv[j4 * 4 + 3] = fmaf(p, vv.w, accv[j4 * 4 + 3]);
            }
        }
    }
    float inv = 1.f / lsum;
    bf16* orow = o + ((size_t)(b * T_) + qt * 64 + qlocal) * C_ + h * 64 + kb;
#pragma unroll
    for (int jd = 0; jd < 16; ++jd) orow[jd] = (bf16)(accv[jd] * inv);
}

// ---------------------------------------------------------------------------
// Launch
// ---------------------------------------------------------------------------
extern "C" void kernel_launch(void* const* d_in, const int* in_sizes, int n_in,
                              void* d_out, int out_size, void* d_ws, size_t ws_size,
                              hipStream_t stream) {
    (void)in_sizes; (void)n_in; (void)out_size; (void)ws_size;
    const int*   idx  = (const int*)d_in[0];
    const int*   y    = (const int*)d_in[1];
    const float* tok  = (const float*)d_in[2];
    const float* pos  = (const float*)d_in[3];
    const float* cls  = (const float*)d_in[4];
    const float* ln1w = (const float*)d_in[5];
    const float* ln1b = (const float*)d_in[6];
    const float* aw   = (const float*)d_in[7];
    const float* ab   = (const float*)d_in[8];
    const float* pw   = (const float*)d_in[9];
    const float* pb   = (const float*)d_in[10];
    const float* ln2w = (const float*)d_in[11];
    const float* ln2b = (const float*)d_in[12];
    const float* w1   = (const float*)d_in[13];
    const float* b1   = (const float*)d_in[14];
    const float* w2   = (const float*)d_in[15];
    const float* b2   = (const float*)d_in[16];
    const float* lnfw = (const float*)d_in[17];
    const float* lnfb = (const float*)d_in[18];
    const float* hw   = (const float*)d_in[19];
    float* out = (float*)d_out;

    // Workspace (≈228 MB): x | qkv(∪ mid) | hbf | bf16 transposed weights
    char* wsp = (char*)d_ws;
    float* x   = (float*)wsp;  wsp += (size_t)M_ * C_  * 4;
    float* qkv = (float*)wsp;  wsp += (size_t)M_ * C3_ * 4;
    bf16*  hbf = (bf16*)wsp;   wsp += (size_t)M_ * C_  * 2;
    bf16*  awt = (bf16*)wsp;   wsp += (size_t)L_ * C_  * C3_ * 2;
    bf16*  pwt = (bf16*)wsp;   wsp += (size_t)L_ * C_  * C_  * 2;
    bf16*  w1t = (bf16*)wsp;   wsp += (size_t)L_ * C_  * C4_ * 2;
    bf16*  w2t = (bf16*)wsp;   wsp += (size_t)L_ * C4_ * C_  * 2;
    bf16*  hwt = (bf16*)wsp;   wsp += (size_t)C_ * V_ * 2;
    bf16*  mid = (bf16*)qkv;   // mlp hidden overlaps qkv (dead after attention)

    // Weight transpose+cast (every call: ws is re-poisoned each launch)
    wt_kernel<<<dim3(C3_ / 32, C_ / 32, L_), 256, 0, stream>>>(aw, awt, C_, C3_);
    wt_kernel<<<dim3(C_ / 32, C_ / 32, L_), 256, 0, stream>>>(pw, pwt, C_, C_);
    wt_kernel<<<dim3(C4_ / 32, C_ / 32, L_), 256, 0, stream>>>(w1, w1t, C_, C4_);
    wt_kernel<<<dim3(C_ / 32, C4_ / 32, L_), 256, 0, stream>>>(w2, w2t, C4_, C_);
    wt_kernel<<<dim3(V_ / 32, C_ / 32, 1), 256, 0, stream>>>(hw, hwt, C_, V_);

    embed_kernel<<<M_, 256, 0, stream>>>(idx, y, tok, pos, cls, x);

    for (int l = 0; l < L_; ++l) {
        ln_kernel<<<M_, 256, 0, stream>>>(x, ln1w + l * C_, ln1b + l * C_, hbf);

        mfma_gemm<0, 1, 0, 0><<<dim3(C3_ / 128, M_ / 128), 256, 0, stream>>>(
            hbf, awt + (size_t)l * C_ * C3_, ab + (size_t)l * C3_, nullptr,
            qkv, C_, C3_);

        attn_kernel<<<dim3(T_ / 64, B_ * H_), 256, 0, stream>>>(qkv, hbf);

        mfma_gemm<0, 1, 1, 0><<<dim3(C_ / 128, M_ / 128), 256, 0, stream>>>(
            hbf, pwt + (size_t)l * C_ * C_, pb + (size_t)l * C_, x,
            x, C_, C_);

        ln_kernel<<<M_, 256, 0, stream>>>(x, ln2w + l * C_, ln2b + l * C_, hbf);

        mfma_gemm<1, 1, 0, 1><<<dim3(C4_ / 128, M_ / 128), 256, 0, stream>>>(
            hbf, w1t + (size_t)l * C_ * C4_, b1 + (size_t)l * C4_, nullptr,
            mid, C_, C4_);

        mfma_gemm<0, 1, 1, 0><<<dim3(C_ / 128, M_ / 128), 256, 0, stream>>>(
            mid, w2t + (size_t)l * C4_ * C_, b2 + (size_t)l * C_, x,
            x, C4_, C_);
    }

    ln_kernel<<<M_, 256, 0, stream>>>(x, lnfw, lnfb, hbf);

    mfma_gemm<0, 0, 0, 0><<<dim3(V_ / 128, M_ / 128), 256, 0, stream>>>(
        hbf, hwt, nullptr, nullptr, out, C_, V_);
}

// Round 3
// 3377.983 us; speedup vs baseline: 1.7881x; 1.7881x over previous
//
#include <hip/hip_runtime.h>
#include <math.h>

// Problem constants
#define V_  1024
#define C_  768
#define H_  12
#define L_  8
#define B_  8
#define T_  1024
#define M_  (B_ * T_)      // 8192
#define C3_ (3 * C_)       // 2304
#define C4_ (4 * C_)       // 3072

typedef __bf16 bf16;
typedef __bf16 bf16x8 __attribute__((ext_vector_type(8)));
typedef float  f32x4  __attribute__((ext_vector_type(4)));

// async global->LDS, 16B per lane; LDS dest = wave-uniform base + lane*16
#define GLDS16(g, l) __builtin_amdgcn_global_load_lds(                       \
    (const __attribute__((address_space(1))) void*)(g),                      \
    (__attribute__((address_space(3))) void*)(l), 16, 0, 0)

__device__ __forceinline__ unsigned short bfb(float f) {
    bf16 h = (bf16)f;
    return __builtin_bit_cast(unsigned short, h);
}

// ---------------------------------------------------------------------------
// Embedding (f32)
// ---------------------------------------------------------------------------
__global__ __launch_bounds__(256) void embed_kernel(
    const int* __restrict__ idx, const int* __restrict__ y,
    const float* __restrict__ tok, const float* __restrict__ pos,
    const float* __restrict__ cls, float* __restrict__ x) {
    int row = blockIdx.x;
    int b = row >> 10, t = row & (T_ - 1);
    int tid = threadIdx.x;
    const float* tr = tok + (size_t)idx[row] * C_;
    const float* pr = pos + (size_t)t * C_;
    const float* cr = cls + (size_t)y[b] * C_;
    float* xr = x + (size_t)row * C_;
    for (int c = tid; c < C_; c += 256)
        xr[c] = tr[c] + pr[c] + cr[c];
}

__device__ __forceinline__ float block_sum256(float v, float* red) {
#pragma unroll
    for (int off = 32; off > 0; off >>= 1) v += __shfl_down(v, off);
    __syncthreads();
    if ((threadIdx.x & 63) == 0) red[threadIdx.x >> 6] = v;
    __syncthreads();
    return red[0] + red[1] + red[2] + red[3];
}

// ---------------------------------------------------------------------------
// LayerNorm: f32 in -> bf16 out
// ---------------------------------------------------------------------------
__global__ __launch_bounds__(256) void ln_kernel(
    const float* __restrict__ in, const float* __restrict__ w,
    const float* __restrict__ b, bf16* __restrict__ out) {
    __shared__ float red[4];
    int row = blockIdx.x, tid = threadIdx.x;
    const float* xr = in + (size_t)row * C_;
    float v0 = xr[tid], v1 = xr[tid + 256], v2 = xr[tid + 512];
    float s = block_sum256(v0 + v1 + v2, red);
    float m = s * (1.0f / C_);
    float d0 = v0 - m, d1 = v1 - m, d2 = v2 - m;
    float s2 = block_sum256(d0 * d0 + d1 * d1 + d2 * d2, red);
    float rs = rsqrtf(s2 * (1.0f / C_) + 1e-5f);
    bf16* orow = out + (size_t)row * C_;
    orow[tid]       = (bf16)(d0 * rs * w[tid]       + b[tid]);
    orow[tid + 256] = (bf16)(d1 * rs * w[tid + 256] + b[tid + 256]);
    orow[tid + 512] = (bf16)(d2 * rs * w[tid + 512] + b[tid + 512]);
}

// ---------------------------------------------------------------------------
// Weight transpose + cast: W[K,N] f32 (layer blockIdx.z) -> Wt[N,K] bf16
// ---------------------------------------------------------------------------
__global__ __launch_bounds__(256) void wt_kernel(
    const float* __restrict__ W, bf16* __restrict__ Wt, int K, int N) {
    __shared__ float ts[32][33];
    const size_t sz = (size_t)K * N;
    const float* Ws = W + blockIdx.z * sz;
    bf16* Wts = Wt + blockIdx.z * sz;
    int n0 = blockIdx.x * 32, k0 = blockIdx.y * 32;
    int tx = threadIdx.x & 31, ty = threadIdx.x >> 5;
#pragma unroll
    for (int i = 0; i < 4; ++i)
        ts[ty + i * 8][tx] = Ws[(size_t)(k0 + ty + i * 8) * N + n0 + tx];
    __syncthreads();
#pragma unroll
    for (int i = 0; i < 4; ++i)
        Wts[(size_t)(n0 + ty + i * 8) * K + k0 + tx] = (bf16)ts[tx][ty + i * 8];
}

// ---------------------------------------------------------------------------
// MFMA GEMM: out[M,N] = epi(A[M,K]bf16 @ Bt[N,K]^T + bias) (+res f32)
// 128x128 tile, BK=64, 4 waves. VSPLIT: cols >= 2C go transposed to vt.
// ---------------------------------------------------------------------------
template <int ACT, int BIASF, int RESF, int OBF, int VSPLIT>
__global__ __launch_bounds__(256) void mfma_gemm(
    const bf16* __restrict__ A, const bf16* __restrict__ Bt,
    const float* __restrict__ bias, const float* __restrict__ res,
    void* __restrict__ outp, bf16* __restrict__ vt, int K, int N) {
    __shared__ bf16 As[128 * 64];
    __shared__ bf16 Bs[128 * 64];
    const int tid = threadIdx.x;
    const int lane = tid & 63, wave = tid >> 6;
    const int wr = (wave >> 1) * 64, wc = (wave & 1) * 64;
    const int brow = blockIdx.y * 128, bcol = blockIdx.x * 128;
    const int l15 = lane & 15, l4 = lane >> 4;

    const bf16* Ab = A + (size_t)brow * K;
    const bf16* Bb = Bt + (size_t)bcol * K;

    f32x4 acc[4][4];
#pragma unroll
    for (int m = 0; m < 4; ++m)
#pragma unroll
        for (int n = 0; n < 4; ++n)
            acc[m][n] = (f32x4){0.f, 0.f, 0.f, 0.f};

    for (int kt = 0; kt < K; kt += 64) {
        __syncthreads();
#pragma unroll
        for (int i = 0; i < 4; ++i) {
            int j = i * 256 + tid;
            GLDS16(Ab + (size_t)(j >> 3) * K + kt + (j & 7) * 8, As + j * 8);
        }
#pragma unroll
        for (int i = 0; i < 4; ++i) {
            int j = i * 256 + tid;
            GLDS16(Bb + (size_t)(j >> 3) * K + kt + (j & 7) * 8, Bs + j * 8);
        }
        __syncthreads();
#pragma unroll
        for (int kk = 0; kk < 2; ++kk) {
            bf16x8 af[4], bfr[4];
#pragma unroll
            for (int m = 0; m < 4; ++m)
                af[m] = *(const bf16x8*)(As + (wr + m * 16 + l15) * 64 + kk * 32 + l4 * 8);
#pragma unroll
            for (int n = 0; n < 4; ++n)
                bfr[n] = *(const bf16x8*)(Bs + (wc + n * 16 + l15) * 64 + kk * 32 + l4 * 8);
#pragma unroll
            for (int m = 0; m < 4; ++m)
#pragma unroll
                for (int n = 0; n < 4; ++n)
                    acc[m][n] = __builtin_amdgcn_mfma_f32_16x16x32_bf16(
                        af[m], bfr[n], acc[m][n], 0, 0, 0);
        }
    }

    // epilogue: C/D layout col=lane&15, row=(lane>>4)*4+reg
    if (VSPLIT && bcol >= 2 * C_) {
        // V third of qkv: write transposed to vt[(b*H+h)*64+d][t] (bf16)
#pragma unroll
        for (int n = 0; n < 4; ++n) {
            const int col = bcol + wc + n * 16 + l15;
            const float bv = BIASF ? bias[col] : 0.f;
            const int hh = (col - 2 * C_) >> 6;
            const int dd = (col - 2 * C_) & 63;
#pragma unroll
            for (int m = 0; m < 4; ++m) {
                const int row0 = brow + wr + m * 16 + l4 * 4;
                const int bq = row0 >> 10, t0 = row0 & (T_ - 1);
                ushort4 pk;
                pk.x = bfb(acc[m][n][0] + bv);
                pk.y = bfb(acc[m][n][1] + bv);
                pk.z = bfb(acc[m][n][2] + bv);
                pk.w = bfb(acc[m][n][3] + bv);
                *(ushort4*)&vt[(((size_t)bq * H_ + hh) * 64 + dd) * T_ + t0] = pk;
            }
        }
        return;
    }
#pragma unroll
    for (int n = 0; n < 4; ++n) {
        const int col = bcol + wc + n * 16 + l15;
        const float bv = BIASF ? bias[col] : 0.f;
#pragma unroll
        for (int m = 0; m < 4; ++m) {
#pragma unroll
            for (int j = 0; j < 4; ++j) {
                const int row = brow + wr + m * 16 + l4 * 4 + j;
                float v = acc[m][n][j] + bv;
                if (ACT == 1) v = 0.5f * v * (1.f + erff(v * 0.70710678118654752440f));
                if (RESF) v += res[(size_t)row * N + col];
                if (OBF)  ((bf16*)outp)[(size_t)row * N + col] = (bf16)v;
                else      ((float*)outp)[(size_t)row * N + col] = v;
            }
        }
    }
}

// ---------------------------------------------------------------------------
// MFMA flash attention. One block per (b, h, 64 q-rows), 4 waves x 16 q-rows.
// qkv bf16 [M,3C] (Q at h*64, K at C+h*64); vt bf16 [(b*H+h)*64+d][t].
// All LDS tiles use 16B-block XOR swizzle: byte = row*128 + (cb ^ ((row&7)<<4)),
// staged via pre-swizzled global source (swizzle applied both sides).
// ---------------------------------------------------------------------------
#define SCL2E 0.18033688011112042592f   // 0.125 * log2(e)

__global__ __launch_bounds__(256) void attn_kernel(
    const bf16* __restrict__ qkv, const bf16* __restrict__ vtb,
    bf16* __restrict__ o) {
    __shared__ bf16 Qs[64 * 64];
    __shared__ bf16 Ks[64 * 64];
    __shared__ bf16 Vt[64 * 64];   // [d][k]
    __shared__ bf16 Ps[4][16 * 64];

    const int qt = gridDim.x - 1 - blockIdx.x;   // heavy tiles first
    const int bh = blockIdx.y;
    const int b = bh / H_, h = bh % H_;
    const int tid = threadIdx.x;
    const int w = tid >> 6, lane = tid & 63;
    const int l15 = lane & 15, g = lane >> 4;

    const bf16* Qg = qkv + ((size_t)(b * T_) + qt * 64) * C3_ + h * 64;
    const bf16* Kg = qkv + (size_t)(b * T_) * C3_ + C_ + h * 64;
    const bf16* Vg = vtb + (size_t)bh * 64 * T_;

    // stage Q (swizzled source -> linear LDS)
#pragma unroll
    for (int i = 0; i < 2; ++i) {
        int j = i * 256 + tid;
        int r = j >> 3, bb = j & 7;
        GLDS16(Qg + (size_t)r * C3_ + ((bb ^ (r & 7)) << 3), Qs + j * 8);
    }

    f32x4 acc_o[4];
#pragma unroll
    for (int n = 0; n < 4; ++n) acc_o[n] = (f32x4){0.f, 0.f, 0.f, 0.f};
    float mrun[4], lsum[4];
#pragma unroll
    for (int j = 0; j < 4; ++j) { mrun[j] = -1e30f; lsum[j] = 0.f; }

    for (int kt = 0; kt <= qt; ++kt) {
        __syncthreads();   // waves done reading previous K/V tiles
#pragma unroll
        for (int i = 0; i < 2; ++i) {
            int j = i * 256 + tid;
            int r = j >> 3, bb = j & 7;
            GLDS16(Kg + (size_t)(kt * 64 + r) * C3_ + ((bb ^ (r & 7)) << 3),
                   Ks + j * 8);
        }
#pragma unroll
        for (int i = 0; i < 2; ++i) {
            int j = i * 256 + tid;
            int r = j >> 3, bb = j & 7;   // r = d-row
            GLDS16(Vg + (size_t)r * T_ + kt * 64 + ((bb ^ (r & 7)) << 3),
                   Vt + j * 8);
        }
        __syncthreads();   // vmcnt(0) drain

        // ---- QK^T: S[16q x 64k] per wave ----
        f32x4 acc_s[4];
#pragma unroll
        for (int n = 0; n < 4; ++n) acc_s[n] = (f32x4){0.f, 0.f, 0.f, 0.f};
#pragma unroll
        for (int kk = 0; kk < 2; ++kk) {
            const int cb = kk * 64 + g * 16;
            const int qrow = w * 16 + l15;
            bf16x8 aq = *(const bf16x8*)((const char*)Qs + qrow * 128 +
                                         (cb ^ ((qrow & 7) << 4)));
#pragma unroll
            for (int n = 0; n < 4; ++n) {
                const int krow = n * 16 + l15;
                bf16x8 bk = *(const bf16x8*)((const char*)Ks + krow * 128 +
                                             (cb ^ ((krow & 7) << 4)));
                acc_s[n] = __builtin_amdgcn_mfma_f32_16x16x32_bf16(
                    aq, bk, acc_s[n], 0, 0, 0);
            }
        }

        // ---- online softmax (raw scores; scale folded into exp2) ----
        const bool diag = (kt == qt);
#pragma unroll
        for (int j = 0; j < 4; ++j) {
            const int qloc = w * 16 + g * 4 + j;
            float sv[4];
#pragma unroll
            for (int n = 0; n < 4; ++n) {
                sv[n] = acc_s[n][j];
                if (diag && (n * 16 + l15 > qloc)) sv[n] = -1e30f;
            }
            float rm = fmaxf(fmaxf(sv[0], sv[1]), fmaxf(sv[2], sv[3]));
            rm = fmaxf(rm, __shfl_xor(rm, 1));
            rm = fmaxf(rm, __shfl_xor(rm, 2));
            rm = fmaxf(rm, __shfl_xor(rm, 4));
            rm = fmaxf(rm, __shfl_xor(rm, 8));
            float mnew = fmaxf(mrun[j], rm);
            float fs = exp2f((mrun[j] - mnew) * SCL2E);
            mrun[j] = mnew;
            float ps = 0.f;
            float pv[4];
#pragma unroll
            for (int n = 0; n < 4; ++n) {
                pv[n] = exp2f((sv[n] - mnew) * SCL2E);
                ps += pv[n];
            }
            ps += __shfl_xor(ps, 1);
            ps += __shfl_xor(ps, 2);
            ps += __shfl_xor(ps, 4);
            ps += __shfl_xor(ps, 8);
            lsum[j] = lsum[j] * fs + ps;
#pragma unroll
            for (int n = 0; n < 4; ++n) acc_o[n][j] *= fs;
            // P -> LDS (pair-packed u32, swizzled; rows are wave-private)
            const int row = g * 4 + j;
#pragma unroll
            for (int n = 0; n < 4; ++n) {
                float po = __shfl_xor(pv[n], 1);
                float lo = (l15 & 1) ? po : pv[n];
                float hi = (l15 & 1) ? pv[n] : po;
                unsigned int u = ((unsigned int)bfb(hi) << 16) | bfb(lo);
                if ((n >> 1) == (l15 & 1)) {
                    int cb = n * 32 + ((l15 & 14) << 1);
                    *(unsigned int*)((char*)Ps[w] + row * 128 +
                                     (cb ^ ((row & 7) << 4))) = u;
                }
            }
        }
        __threadfence_block();   // P writes visible before fragment reads

        // ---- PV: O += P[16q x 64k] * V[64k x 64d] ----
#pragma unroll
        for (int kk = 0; kk < 2; ++kk) {
            const int cb = kk * 64 + g * 16;
            bf16x8 ap = *(const bf16x8*)((const char*)Ps[w] + l15 * 128 +
                                         (cb ^ ((l15 & 7) << 4)));
#pragma unroll
            for (int n = 0; n < 4; ++n) {
                const int drow = n * 16 + l15;
                bf16x8 bv = *(const bf16x8*)((const char*)Vt + drow * 128 +
                                             (cb ^ ((drow & 7) << 4)));
                acc_o[n] = __builtin_amdgcn_mfma_f32_16x16x32_bf16(
                    ap, bv, acc_o[n], 0, 0, 0);
            }
        }
    }

    // ---- write O ----
#pragma unroll
    for (int j = 0; j < 4; ++j) {
        const float inv = 1.f / lsum[j];
        const int orow = qt * 64 + w * 16 + g * 4 + j;
        bf16* op = o + ((size_t)(b * T_) + orow) * C_ + h * 64;
#pragma unroll
        for (int n = 0; n < 4; ++n)
            op[n * 16 + l15] = (bf16)(acc_o[n][j] * inv);
    }
}

// ---------------------------------------------------------------------------
// Launch
// ---------------------------------------------------------------------------
extern "C" void kernel_launch(void* const* d_in, const int* in_sizes, int n_in,
                              void* d_out, int out_size, void* d_ws, size_t ws_size,
                              hipStream_t stream) {
    (void)in_sizes; (void)n_in; (void)out_size; (void)ws_size;
    const int*   idx  = (const int*)d_in[0];
    const int*   y    = (const int*)d_in[1];
    const float* tok  = (const float*)d_in[2];
    const float* pos  = (const float*)d_in[3];
    const float* cls  = (const float*)d_in[4];
    const float* ln1w = (const float*)d_in[5];
    const float* ln1b = (const float*)d_in[6];
    const float* aw   = (const float*)d_in[7];
    const float* ab   = (const float*)d_in[8];
    const float* pw   = (const float*)d_in[9];
    const float* pb   = (const float*)d_in[10];
    const float* ln2w = (const float*)d_in[11];
    const float* ln2b = (const float*)d_in[12];
    const float* w1   = (const float*)d_in[13];
    const float* b1   = (const float*)d_in[14];
    const float* w2   = (const float*)d_in[15];
    const float* b2   = (const float*)d_in[16];
    const float* lnfw = (const float*)d_in[17];
    const float* lnfb = (const float*)d_in[18];
    const float* hw   = (const float*)d_in[19];
    float* out = (float*)d_out;

    // Workspace: x(f32) | union{qkv bf16 + vt bf16 | mid bf16} | hbf | weights
    char* wsp = (char*)d_ws;
    float* x   = (float*)wsp;  wsp += (size_t)M_ * C_ * 4;
    char*  uni = wsp;          wsp += (size_t)M_ * C4_ * 2;   // 50.3 MB union
    bf16*  qkv = (bf16*)uni;                                   // M x 3C
    bf16*  vtb = (bf16*)(uni + (size_t)M_ * C3_ * 2);          // B*H*64 x T
    bf16*  mid = (bf16*)uni;                                   // M x 4C
    bf16*  hbf = (bf16*)wsp;   wsp += (size_t)M_ * C_ * 2;
    bf16*  awt = (bf16*)wsp;   wsp += (size_t)L_ * C_ * C3_ * 2;
    bf16*  pwt = (bf16*)wsp;   wsp += (size_t)L_ * C_ * C_  * 2;
    bf16*  w1t = (bf16*)wsp;   wsp += (size_t)L_ * C_ * C4_ * 2;
    bf16*  w2t = (bf16*)wsp;   wsp += (size_t)L_ * C4_ * C_ * 2;
    bf16*  hwt = (bf16*)wsp;   wsp += (size_t)C_ * V_ * 2;

    wt_kernel<<<dim3(C3_ / 32, C_ / 32, L_), 256, 0, stream>>>(aw, awt, C_, C3_);
    wt_kernel<<<dim3(C_ / 32, C_ / 32, L_), 256, 0, stream>>>(pw, pwt, C_, C_);
    wt_kernel<<<dim3(C4_ / 32, C_ / 32, L_), 256, 0, stream>>>(w1, w1t, C_, C4_);
    wt_kernel<<<dim3(C_ / 32, C4_ / 32, L_), 256, 0, stream>>>(w2, w2t, C4_, C_);
    wt_kernel<<<dim3(V_ / 32, C_ / 32, 1), 256, 0, stream>>>(hw, hwt, C_, V_);

    embed_kernel<<<M_, 256, 0, stream>>>(idx, y, tok, pos, cls, x);

    for (int l = 0; l < L_; ++l) {
        ln_kernel<<<M_, 256, 0, stream>>>(x, ln1w + l * C_, ln1b + l * C_, hbf);

        mfma_gemm<0, 1, 0, 1, 1><<<dim3(C3_ / 128, M_ / 128), 256, 0, stream>>>(
            hbf, awt + (size_t)l * C_ * C3_, ab + (size_t)l * C3_, nullptr,
            qkv, vtb, C_, C3_);

        attn_kernel<<<dim3(T_ / 64, B_ * H_), 256, 0, stream>>>(qkv, vtb, hbf);

        mfma_gemm<0, 1, 1, 0, 0><<<dim3(C_ / 128, M_ / 128), 256, 0, stream>>>(
            hbf, pwt + (size_t)l * C_ * C_, pb + (size_t)l * C_, x,
            x, nullptr, C_, C_);

        ln_kernel<<<M_, 256, 0, stream>>>(x, ln2w + l * C_, ln2b + l * C_, hbf);

        mfma_gemm<1, 1, 0, 1, 0><<<dim3(C4_ / 128, M_ / 128), 256, 0, stream>>>(
            hbf, w1t + (size_t)l * C_ * C4_, b1 + (size_t)l * C4_, nullptr,
            mid, nullptr, C_, C4_);

        mfma_gemm<0, 1, 1, 0, 0><<<dim3(C_ / 128, M_ / 128), 256, 0, stream>>>(
            mid, w2t + (size_t)l * C4_ * C_, b2 + (size_t)l * C_, x,
            x, nullptr, C4_, C_);
    }

    ln_kernel<<<M_, 256, 0, stream>>>(x, lnfw, lnfb, hbf);

    mfma_gemm<0, 0, 0, 0, 0><<<dim3(V_ / 128, M_ / 128), 256, 0, stream>>>(
        hbf, hwt, nullptr, nullptr, out, nullptr, C_, V_);
}